// Round 1
// baseline (3376.191 us; speedup 1.0000x reference)
//
#include <hip/hip_runtime.h>
#include <math.h>

#define RBF 32
#define BLOCK 256

// out[a,i] = sum_b cross(F1[a,b,:], L[b,:])_i
// F1[a,b,:] = unit(rij[a,b]) * radial[a,b]
// radial[a,b] = W2 . softplus(rbf[a,b,:] @ W1 + b1) + b2, masked if |rij|<1e-8
__global__ __launch_bounds__(BLOCK, 2)
void f1o1_kernel(const float* __restrict__ L,     // [N,3]
                 const float* __restrict__ rbf,   // [N,N,RBF]
                 const float* __restrict__ rij,   // [N,N,3]
                 const float* __restrict__ W1,    // [RBF,RBF]
                 const float* __restrict__ b1,    // [RBF]
                 const float* __restrict__ W2,    // [RBF]
                 const float* __restrict__ b2,    // [1]
                 float* __restrict__ out,         // [N,3]
                 int N)
{
    __shared__ float sW1[RBF * RBF];
    __shared__ float sb1[RBF];
    __shared__ float sW2[RBF];
    __shared__ float sred[4 * 3];

    const int t = threadIdx.x;
    const int a = blockIdx.x;

    for (int i = t; i < RBF * RBF; i += BLOCK) sW1[i] = W1[i];
    if (t < RBF) { sb1[t] = b1[t]; sW2[t] = W2[t]; }
    __syncthreads();

    const float bias2 = b2[0];
    float acc0 = 0.f, acc1 = 0.f, acc2 = 0.f;
    const size_t abase = (size_t)a * (size_t)N;

    for (int b0 = 2 * t; b0 < N; b0 += 2 * BLOCK) {
        // ---- load two adjacent rbf rows (2 x 32 floats, contiguous 256 B) ----
        const float4* rp = (const float4*)(rbf + (abase + (size_t)b0) * RBF);
        float4 xa[RBF / 4], xb[RBF / 4];
        #pragma unroll
        for (int q = 0; q < RBF / 4; ++q) xa[q] = rp[q];
        #pragma unroll
        for (int q = 0; q < RBF / 4; ++q) xb[q] = rp[RBF / 4 + q];

        // ---- Dense1: h = rbf_row @ W1 + b1 (W1 broadcast from LDS) ----
        float ha[RBF], hb[RBF];
        #pragma unroll
        for (int j = 0; j < RBF; ++j) { float v = sb1[j]; ha[j] = v; hb[j] = v; }

        #pragma unroll
        for (int q = 0; q < RBF / 4; ++q) {
            const float xsa[4] = {xa[q].x, xa[q].y, xa[q].z, xa[q].w};
            const float xsb[4] = {xb[q].x, xb[q].y, xb[q].z, xb[q].w};
            #pragma unroll
            for (int rr = 0; rr < 4; ++rr) {
                const int r = q * 4 + rr;
                const float4* w4 = (const float4*)(sW1 + r * RBF);
                #pragma unroll
                for (int jq = 0; jq < RBF / 4; ++jq) {
                    float4 w = w4[jq];
                    ha[jq*4+0] = fmaf(xsa[rr], w.x, ha[jq*4+0]);
                    ha[jq*4+1] = fmaf(xsa[rr], w.y, ha[jq*4+1]);
                    ha[jq*4+2] = fmaf(xsa[rr], w.z, ha[jq*4+2]);
                    ha[jq*4+3] = fmaf(xsa[rr], w.w, ha[jq*4+3]);
                    hb[jq*4+0] = fmaf(xsb[rr], w.x, hb[jq*4+0]);
                    hb[jq*4+1] = fmaf(xsb[rr], w.y, hb[jq*4+1]);
                    hb[jq*4+2] = fmaf(xsb[rr], w.z, hb[jq*4+2]);
                    hb[jq*4+3] = fmaf(xsb[rr], w.w, hb[jq*4+3]);
                }
            }
        }

        // ---- softplus + Dense2 ----
        float ra = bias2, rb = bias2;
        #pragma unroll
        for (int j = 0; j < RBF; ++j) {
            float va = ha[j];
            float spa = fmaxf(va, 0.f) + __logf(1.f + __expf(-fabsf(va)));
            ra = fmaf(spa, sW2[j], ra);
            float vb = hb[j];
            float spb = fmaxf(vb, 0.f) + __logf(1.f + __expf(-fabsf(vb)));
            rb = fmaf(spb, sW2[j], rb);
        }

        // ---- mask, unit vector, cross with L, accumulate ----
        const float* rr3 = rij + (abase + (size_t)b0) * 3;
        #pragma unroll
        for (int u = 0; u < 2; ++u) {
            float radial = (u == 0) ? ra : rb;
            float r0 = rr3[u*3+0], r1 = rr3[u*3+1], r2 = rr3[u*3+2];
            float ss = r0*r0 + r1*r1 + r2*r2;
            // dij < 1e-8  <=>  ss < 1e-16
            float scale = (ss < 1e-16f) ? 0.f : radial * rsqrtf(fmaxf(ss, 1e-8f));
            float f0 = r0 * scale, f1 = r1 * scale, f2 = r2 * scale;
            const float* lp = L + (size_t)(b0 + u) * 3;
            float l0 = lp[0], l1 = lp[1], l2 = lp[2];
            acc0 += f1 * l2 - f2 * l1;
            acc1 += f2 * l0 - f0 * l2;
            acc2 += f0 * l1 - f1 * l0;
        }
    }

    // ---- wave reduction (64 lanes) ----
    #pragma unroll
    for (int off = 32; off > 0; off >>= 1) {
        acc0 += __shfl_down(acc0, off, 64);
        acc1 += __shfl_down(acc1, off, 64);
        acc2 += __shfl_down(acc2, off, 64);
    }
    const int wv = t >> 6;
    if ((t & 63) == 0) {
        sred[wv * 3 + 0] = acc0;
        sred[wv * 3 + 1] = acc1;
        sred[wv * 3 + 2] = acc2;
    }
    __syncthreads();
    if (t < 3) {
        out[(size_t)a * 3 + t] = sred[t] + sred[3 + t] + sred[6 + t] + sred[9 + t];
    }
}

extern "C" void kernel_launch(void* const* d_in, const int* in_sizes, int n_in,
                              void* d_out, int out_size, void* d_ws, size_t ws_size,
                              hipStream_t stream) {
    const float* L   = (const float*)d_in[0];  // layer_input [N,1,3]
    const float* rbf = (const float*)d_in[1];  // rbf_inputs [N,N,32]
    const float* rij = (const float*)d_in[2];  // rij [N,N,3]
    const float* W1  = (const float*)d_in[3];
    const float* b1  = (const float*)d_in[4];
    const float* W2  = (const float*)d_in[5];
    const float* b2  = (const float*)d_in[6];
    float* out = (float*)d_out;

    const int N = in_sizes[0] / 3;  // 2048

    f1o1_kernel<<<N, BLOCK, 0, stream>>>(L, rbf, rij, W1, b1, W2, b2, out, N);
}

// Round 2
// 3339.121 us; speedup vs baseline: 1.0111x; 1.0111x over previous
//
#include <hip/hip_runtime.h>
#include <math.h>

#define RBF 32
#define BLOCK 256

// out[a,i] = sum_b cross(F1[a,b,:], L[b,:])_i
// F1[a,b,:] = unit(rij[a,b]) * radial[a,b]
// radial[a,b] = W2 . softplus(rbf[a,b,:] @ W1 + b1) + b2, masked if |rij|<1e-8
//
// Round-1 lesson: preloading 2x32 x-values + 2x32 h-accumulators spilled
// (WRITE_SIZE 2 GB). Now: h stays in 16 float4 regs; x is streamed one
// float4 per row per k-chunk with manual double-buffering (16 regs live).
__global__ __launch_bounds__(BLOCK, 2)
void f1o1_kernel(const float* __restrict__ L,     // [N,3]
                 const float* __restrict__ rbf,   // [N,N,RBF]
                 const float* __restrict__ rij,   // [N,N,3]
                 const float* __restrict__ W1,    // [RBF,RBF]
                 const float* __restrict__ b1,    // [RBF]
                 const float* __restrict__ W2,    // [RBF]
                 const float* __restrict__ b2,    // [1]
                 float* __restrict__ out,         // [N,3]
                 int N)
{
    __shared__ float sW1[RBF * RBF];
    __shared__ float sb1[RBF];
    __shared__ float sW2[RBF];
    __shared__ float sred[4 * 3];

    const int t = threadIdx.x;
    const int a = blockIdx.x;

    for (int i = t; i < RBF * RBF; i += BLOCK) sW1[i] = W1[i];
    if (t < RBF) { sb1[t] = b1[t]; sW2[t] = W2[t]; }
    __syncthreads();

    const float bias2 = b2[0];
    float acc0 = 0.f, acc1 = 0.f, acc2 = 0.f;
    const size_t abase = (size_t)a * (size_t)N;

    for (int b0 = 2 * t; b0 < N; b0 += 2 * BLOCK) {
        const float4* rpa = (const float4*)(rbf + (abase + (size_t)b0) * RBF);
        const float4* rpb = rpa + RBF / 4;

        // h accumulators: 2 rows x 32 cols = 16 float4 registers
        float4 ha[RBF / 4], hb[RBF / 4];
        #pragma unroll
        for (int jq = 0; jq < RBF / 4; ++jq) {
            float4 bv = ((const float4*)sb1)[jq];
            ha[jq] = bv; hb[jq] = bv;
        }

        // stream x in chunks of 4 k's per row, double-buffered
        float4 cxa = rpa[0], cxb = rpb[0];
        #pragma unroll
        for (int q = 0; q < RBF / 4; ++q) {
            float4 nxa, nxb;
            if (q + 1 < RBF / 4) { nxa = rpa[q + 1]; nxb = rpb[q + 1]; }
            #pragma unroll
            for (int rr = 0; rr < 4; ++rr) {
                const float xsa = (rr == 0) ? cxa.x : (rr == 1) ? cxa.y : (rr == 2) ? cxa.z : cxa.w;
                const float xsb = (rr == 0) ? cxb.x : (rr == 1) ? cxb.y : (rr == 2) ? cxb.z : cxb.w;
                const int k = q * 4 + rr;
                const float4* w4 = (const float4*)(sW1 + k * RBF);
                #pragma unroll
                for (int jq = 0; jq < RBF / 4; ++jq) {
                    float4 w = w4[jq];
                    ha[jq].x = fmaf(xsa, w.x, ha[jq].x);
                    ha[jq].y = fmaf(xsa, w.y, ha[jq].y);
                    ha[jq].z = fmaf(xsa, w.z, ha[jq].z);
                    ha[jq].w = fmaf(xsa, w.w, ha[jq].w);
                    hb[jq].x = fmaf(xsb, w.x, hb[jq].x);
                    hb[jq].y = fmaf(xsb, w.y, hb[jq].y);
                    hb[jq].z = fmaf(xsb, w.z, hb[jq].z);
                    hb[jq].w = fmaf(xsb, w.w, hb[jq].w);
                }
            }
            cxa = nxa; cxb = nxb;
        }

        // ---- softplus + Dense2 ----
        float ra = bias2, rb = bias2;
        #pragma unroll
        for (int jq = 0; jq < RBF / 4; ++jq) {
            float4 w2v = ((const float4*)sW2)[jq];
            const float hav[4] = {ha[jq].x, ha[jq].y, ha[jq].z, ha[jq].w};
            const float hbv[4] = {hb[jq].x, hb[jq].y, hb[jq].z, hb[jq].w};
            const float w2s[4] = {w2v.x, w2v.y, w2v.z, w2v.w};
            #pragma unroll
            for (int c = 0; c < 4; ++c) {
                float va = hav[c];
                float spa = fmaxf(va, 0.f) + __logf(1.f + __expf(-fabsf(va)));
                ra = fmaf(spa, w2s[c], ra);
                float vb = hbv[c];
                float spb = fmaxf(vb, 0.f) + __logf(1.f + __expf(-fabsf(vb)));
                rb = fmaf(spb, w2s[c], rb);
            }
        }

        // ---- mask, unit vector, cross with L, accumulate ----
        const float* rr3 = rij + (abase + (size_t)b0) * 3;
        #pragma unroll
        for (int u = 0; u < 2; ++u) {
            float radial = (u == 0) ? ra : rb;
            float r0 = rr3[u*3+0], r1 = rr3[u*3+1], r2 = rr3[u*3+2];
            float ss = r0*r0 + r1*r1 + r2*r2;
            // dij < 1e-8  <=>  ss < 1e-16
            float scale = (ss < 1e-16f) ? 0.f : radial * rsqrtf(fmaxf(ss, 1e-8f));
            float f0 = r0 * scale, f1 = r1 * scale, f2 = r2 * scale;
            const float* lp = L + (size_t)(b0 + u) * 3;
            float l0 = lp[0], l1 = lp[1], l2 = lp[2];
            acc0 += f1 * l2 - f2 * l1;
            acc1 += f2 * l0 - f0 * l2;
            acc2 += f0 * l1 - f1 * l0;
        }
    }

    // ---- wave reduction (64 lanes) ----
    #pragma unroll
    for (int off = 32; off > 0; off >>= 1) {
        acc0 += __shfl_down(acc0, off, 64);
        acc1 += __shfl_down(acc1, off, 64);
        acc2 += __shfl_down(acc2, off, 64);
    }
    const int wv = t >> 6;
    if ((t & 63) == 0) {
        sred[wv * 3 + 0] = acc0;
        sred[wv * 3 + 1] = acc1;
        sred[wv * 3 + 2] = acc2;
    }
    __syncthreads();
    if (t < 3) {
        out[(size_t)a * 3 + t] = sred[t] + sred[3 + t] + sred[6 + t] + sred[9 + t];
    }
}

extern "C" void kernel_launch(void* const* d_in, const int* in_sizes, int n_in,
                              void* d_out, int out_size, void* d_ws, size_t ws_size,
                              hipStream_t stream) {
    const float* L   = (const float*)d_in[0];  // layer_input [N,1,3]
    const float* rbf = (const float*)d_in[1];  // rbf_inputs [N,N,32]
    const float* rij = (const float*)d_in[2];  // rij [N,N,3]
    const float* W1  = (const float*)d_in[3];
    const float* b1  = (const float*)d_in[4];
    const float* W2  = (const float*)d_in[5];
    const float* b2  = (const float*)d_in[6];
    float* out = (float*)d_out;

    const int N = in_sizes[0] / 3;  // 2048

    f1o1_kernel<<<N, BLOCK, 0, stream>>>(L, rbf, rij, W1, b1, W2, b2, out, N);
}